// Round 4
// baseline (130.222 us; speedup 1.0000x reference)
//
#include <hip/hip_runtime.h>
#include <math.h>

#define T_GRID 2048
#define NC 2048
#define NT 2048
#define BATCH 16
#define XCUT 28.0f        // exp2(-0.72135*28) ~ 2^-20 per-point truncation
#define TILE 112
#define BW 132
#define PCAP 768          // filtered-point LDS capacity (expected ~245)
#define NSB 32            // sub-bins for per-t windowing

// =====================================================================
// K_A: per-tile fused  minmax -> filter+bucket -> h (RBF smoother) -> conv x4
// grid (19, 16), 256 threads. Writes f (float2 per grid point) and mm.
// =====================================================================
__global__ __launch_bounds__(256) void k_fused(
        const float4* __restrict__ xc4, const float4* __restrict__ xt4,
        const float* __restrict__ xc, const float* __restrict__ yc,
        const float* __restrict__ ls_psi, const float* __restrict__ os_psi,
        const float* __restrict__ w1, const float* __restrict__ b1,
        const float* __restrict__ w2, const float* __restrict__ b2,
        const float* __restrict__ w3, const float* __restrict__ b3,
        const float* __restrict__ w4, const float* __restrict__ b4,
        float* __restrict__ mm, float* __restrict__ f) {
    __shared__ float rep[3][BW];
    __shared__ float L1s[16][BW];                 // layer-1 out; later aliased as layer-3 out
    __shared__ __align__(16) char pool[32 * BW * 4];  // 16896 B: layer-2 out; early: pts/part/bins
    __shared__ float w1L[15][16];
    __shared__ float w2L[80][32];
    __shared__ float w3L[160][16];
    __shared__ float w4L[80][2];
    __shared__ float bL[66];

    float (*L2s)[BW] = reinterpret_cast<float (*)[BW]>(pool);
    float (*L3s)[BW] = L1s;                       // alias: L1 dead after layer 2
    float2* pts    = reinterpret_cast<float2*>(pool);            // [0, 6144)
    float2* part   = reinterpret_cast<float2*>(pool + 6144);     // [6144, 8192)
    int*    bstart = reinterpret_cast<int*>(pool + 8192);        // 33 ints [8192, 8324)
    int*    curi   = reinterpret_cast<int*>(pool + 8336);        // 32 ints [8336, 8464)
    float*  bc     = reinterpret_cast<float*>(pool + 8464);      // 2 floats broadcast

    int tid = threadIdx.x;
    int b = blockIdx.y;
    int gstart = blockIdx.x * TILE - 8;

    // ---- stage weights/biases (independent of everything; loads issue early) ----
    for (int idx = tid; idx < 240; idx += 256)  { int o = idx / 15,  r2 = idx % 15;  w1L[r2][o] = w1[idx]; }
    for (int idx = tid; idx < 2560; idx += 256) { int o = idx / 80,  r2 = idx % 80;  w2L[r2][o] = w2[idx]; }
    for (int idx = tid; idx < 2560; idx += 256) { int o = idx / 160, r2 = idx % 160; w3L[r2][o] = w3[idx]; }
    for (int idx = tid; idx < 160; idx += 256)  { int o = idx / 80,  r2 = idx % 80;  w4L[r2][o] = w4[idx]; }
    if (tid < 16) bL[tid] = b1[tid];
    if (tid < 32) bL[16 + tid] = b2[tid];
    if (tid < 16) bL[48 + tid] = b3[tid];
    if (tid < 2)  bL[64 + tid] = b4[tid];
    // zero rep / L1 pad columns (cols 0,1,130,131)
    if (tid < 4) {
        int c = (tid < 2) ? tid : tid + 128;
        for (int r2 = 0; r2 < 3; r2++)  rep[r2][c] = 0.f;
        for (int r2 = 0; r2 < 16; r2++) L1s[r2][c] = 0.f;
    }

    // ---- global min/max (every block computes it; exact & order-independent) ----
    float lo = 3.4e38f, hi = -3.4e38f;
    for (int i = tid; i < BATCH * NC / 4; i += 256) {
        float4 v = xc4[i];
        lo = fminf(lo, fminf(fminf(v.x, v.y), fminf(v.z, v.w)));
        hi = fmaxf(hi, fmaxf(fmaxf(v.x, v.y), fmaxf(v.z, v.w)));
    }
    for (int i = tid; i < BATCH * NT / 4; i += 256) {
        float4 v = xt4[i];
        lo = fminf(lo, fminf(fminf(v.x, v.y), fminf(v.z, v.w)));
        hi = fmaxf(hi, fmaxf(fmaxf(v.x, v.y), fmaxf(v.z, v.w)));
    }
    for (int off = 32; off; off >>= 1) {
        lo = fminf(lo, __shfl_down(lo, off));
        hi = fmaxf(hi, __shfl_down(hi, off));
    }
    if ((tid & 63) == 0) part[tid >> 6] = make_float2(lo, hi);
    __syncthreads();
    if (tid == 0) {
        for (int w = 1; w < 4; w++) {
            float2 q = part[w];
            lo = fminf(lo, q.x); hi = fmaxf(hi, q.y);
        }
        bc[0] = lo; bc[1] = hi;
        mm[0] = lo; mm[1] = hi;       // all blocks write identical bits
    }
    __syncthreads();
    float lower = bc[0], upper = bc[1];
    float step = (upper - lower) * (1.0f / (T_GRID - 1));
    float ls = ls_psi[0], os = os_psi[0];
    float c2 = -0.72134752044f / (ls * ls);       // -0.5*log2(e)/ls^2
    float R = ls * sqrtf(XCUT);

    int g0 = max(gstart, 0), g1 = min(gstart + 127, T_GRID - 1);
    float tmin = fmaf((float)g0, step, lower) - R;
    float tmax = fmaf((float)g1, step, lower) + R;
    float sbw_inv = (float)NSB / (tmax - tmin);

    // ---- filter own batch's context points into the tile's box, bucket by NSB sub-bins ----
    if (tid < NSB + 1) bstart[tid] = 0;
    __syncthreads();
    float xv[8], yv[8];
    int bn[8];
    const float* xb = xc + b * NC;
    const float* yb = yc + b * NC;
#pragma unroll
    for (int k = 0; k < 8; k++) {
        int idx = tid + 256 * k;
        xv[k] = xb[idx];
        yv[k] = yb[idx];
        bool in = (xv[k] >= tmin) & (xv[k] <= tmax);
        bn[k] = -1;
        if (in) {
            bn[k] = min(NSB - 1, max(0, (int)((xv[k] - tmin) * sbw_inv)));
            atomicAdd(&bstart[bn[k]], 1);
        }
    }
    __syncthreads();
    if (tid == 0) {        // serial exclusive scan of 32 bins (cheap)
        int run = 0;
        for (int i = 0; i < NSB; i++) { int c = bstart[i]; bstart[i] = run; run += c; }
        bstart[NSB] = run;
    }
    __syncthreads();
    if (tid < NSB) curi[tid] = bstart[tid];
    __syncthreads();
#pragma unroll
    for (int k = 0; k < 8; k++) {
        if (bn[k] >= 0) {
            int pos = atomicAdd(&curi[bn[k]], 1);
            if (pos < PCAP) pts[pos] = make_float2(xv[k], yv[k]);
        }
    }
    __syncthreads();

    // ---- h-phase: 2 threads per position, window limited to overlapping sub-bins ----
    {
        int p = tid & 127, rr = tid >> 7;
        int gp = gstart + p;
        bool pvalid = (gp >= 0 && gp < T_GRID);
        float t = fmaf((float)gp, step, lower);
        int s = 0, e = 0;
        if (pvalid) {
            int b0 = min(NSB - 1, max(0, (int)((t - R - tmin) * sbw_inv)));
            int b1 = min(NSB - 1, max(0, (int)((t + R - tmin) * sbw_inv)));
            s = bstart[b0];
            e = min(bstart[b1 + 1], PCAP);
        }
        float S0 = 0.f, S1 = 0.f;
        for (int j = s + rr; j < e; j += 2) {
            float2 xy = pts[j];
            float d = t - xy.x;
            float ev = exp2f(d * d * c2);
            S0 += ev;
            S1 = fmaf(ev, xy.y, S1);
        }
        __syncthreads();                // pts reads done; part reused below
        part[tid] = make_float2(S0, S1);
        __syncthreads();
        if (tid < 128) {
            float2 q = part[tid + 128];
            S0 += q.x; S1 += q.y;
            float h0 = os * S0;
            float h1 = os * S1 / (h0 + 1e-8f);
            rep[0][p + 2] = pvalid ? t : 0.f;
            rep[1][p + 2] = pvalid ? h0 : 0.f;
            rep[2][p + 2] = pvalid ? h1 : 0.f;
        }
    }
    __syncthreads();                    // pool fully dead; L2s region free from here

    // ---- layer 1: 3 -> 16, relu. o=tid&15, 16 groups x 8 positions ----
    {
        if (tid < 4) {                  // zero L2 pad columns (pool now free)
            int c = (tid < 2) ? tid : tid + 128;
            for (int r2 = 0; r2 < 32; r2++) L2s[r2][c] = 0.f;
        }
        int o = tid & 15, s0 = (tid >> 4) << 3;
        float acc[8];
        float bias = bL[o];
#pragma unroll
        for (int s = 0; s < 8; s++) acc[s] = bias;
        for (int i = 0; i < 3; i++) {
            float x[12];
#pragma unroll
            for (int j = 0; j < 12; j++) x[j] = rep[i][s0 + j];
#pragma unroll
            for (int k = 0; k < 5; k++) {
                float w = w1L[i * 5 + k][o];
#pragma unroll
                for (int s = 0; s < 8; s++) acc[s] = fmaf(x[s + k], w, acc[s]);
            }
        }
        __syncthreads();                // rep reads done before any L1 write hazard? (L1 pads pre-zeroed; strip writes below)
#pragma unroll
        for (int s = 0; s < 8; s++) {
            int p = s0 + s, gp = gstart + p;
            bool vv = (p >= 2 && p < 126 && gp >= 0 && gp < T_GRID);
            L1s[o][p + 2] = vv ? fmaxf(acc[s], 0.f) : 0.f;
        }
    }
    __syncthreads();

    // ---- layer 2: 16 -> 32, relu. o=tid&31, 8 groups x 16 positions ----
    {
        int o = tid & 31, s0 = (tid >> 5) << 4;
        float acc[16];
        float bias = bL[16 + o];
#pragma unroll
        for (int s = 0; s < 16; s++) acc[s] = bias;
        for (int i = 0; i < 16; i++) {
            float x[20];
#pragma unroll
            for (int j = 0; j < 20; j++) x[j] = L1s[i][s0 + j];
#pragma unroll
            for (int k = 0; k < 5; k++) {
                float w = w2L[i * 5 + k][o];
#pragma unroll
                for (int s = 0; s < 16; s++) acc[s] = fmaf(x[s + k], w, acc[s]);
            }
        }
#pragma unroll
        for (int s = 0; s < 16; s++) {
            int p = s0 + s, gp = gstart + p;
            bool vv = (p >= 4 && p < 124 && gp >= 0 && gp < T_GRID);
            L2s[o][p + 2] = vv ? fmaxf(acc[s], 0.f) : 0.f;
        }
    }
    __syncthreads();

    // ---- layer 3: 32 -> 16, relu. writes into L1 storage (L1 dead). ----
    {
        int o = tid & 15, s0 = (tid >> 4) << 3;
        float acc[8];
        float bias = bL[48 + o];
#pragma unroll
        for (int s = 0; s < 8; s++) acc[s] = bias;
        for (int i = 0; i < 32; i++) {
            float x[12];
#pragma unroll
            for (int j = 0; j < 12; j++) x[j] = L2s[i][s0 + j];
#pragma unroll
            for (int k = 0; k < 5; k++) {
                float w = w3L[i * 5 + k][o];
#pragma unroll
                for (int s = 0; s < 8; s++) acc[s] = fmaf(x[s + k], w, acc[s]);
            }
        }
        __syncthreads();                // all L2/L1 reads done before overwriting L1 as L3
#pragma unroll
        for (int s = 0; s < 8; s++) {
            int p = s0 + s, gp = gstart + p;
            bool vv = (p >= 6 && p < 122 && gp >= 0 && gp < T_GRID);
            L3s[o][p + 2] = vv ? fmaxf(acc[s], 0.f) : 0.f;
        }
    }
    __syncthreads();

    // ---- layer 4: 16 -> 2 + softplus; o=tid&1, one position per thread-pair ----
    {
        int o = tid & 1, p = tid >> 1;
        float a = bL[64 + o];
        for (int i = 0; i < 16; i++) {
#pragma unroll
            for (int k = 0; k < 5; k++) {
                a = fmaf(L3s[i][p + k], w4L[i * 5 + k][o], a);
            }
        }
        int gp = gstart + p;
        if (p >= 8 && p < 120 && gp >= 0 && gp < T_GRID) {
            if (o) {
                float sp = fmaxf(a, 0.f) + log1pf(expf(-fabsf(a)));
                f[2 * (b * T_GRID + gp) + 1] = sp;
            } else {
                f[2 * (b * T_GRID + gp)] = a;
            }
        }
    }
}

// =====================================================================
// K_B: windowed out = RBF(xt, t) @ [f_mu, f_sp], 4 threads per xt
// =====================================================================
__global__ __launch_bounds__(256) void k_out(const float* __restrict__ xt,
                                             const float* __restrict__ ls_rho,
                                             const float* __restrict__ os_rho,
                                             const float* __restrict__ mm,
                                             const float2* __restrict__ f,
                                             float2* __restrict__ out) {
    __shared__ float2 sf[T_GRID];
    __shared__ float2 part[256];
    int b = blockIdx.y, tid = threadIdx.x;
    int it = blockIdx.x * 64 + (tid & 63);
    int r = tid >> 6;
    float lower = mm[0], upper = mm[1];
    float step = (upper - lower) * (1.0f / (T_GRID - 1));
    float invstep = 1.0f / step;
    float ls = ls_rho[0], os = os_rho[0];
    float c2 = -0.72134752044f / (ls * ls);
    float R = ls * sqrtf(XCUT);
    float x = xt[b * NT + it];

    const float2* fb = f + b * T_GRID;
    for (int k = tid; k < T_GRID; k += 256) sf[k] = fb[k];
    __syncthreads();

    int j0 = max(0, (int)floorf((x - R - lower) * invstep));
    int j1 = min(T_GRID - 1, (int)ceilf((x + R - lower) * invstep));

    float Smu = 0.f, Ssg = 0.f;
    float jf = (float)(j0 + r);
    for (int j = j0 + r; j <= j1; j += 4) {
        float2 v = sf[j];
        float d = x - fmaf(jf, step, lower);
        float e = exp2f(d * d * c2);
        Smu = fmaf(e, v.x, Smu);
        Ssg = fmaf(e, v.y, Ssg);
        jf += 4.0f;
    }
    part[tid] = make_float2(Smu, Ssg);
    __syncthreads();
    if (r == 0) {
#pragma unroll
        for (int q = 64; q < 256; q += 64) {
            float2 pp = part[tid + q];
            Smu += pp.x; Ssg += pp.y;
        }
        out[b * NT + it] = make_float2(os * Smu, os * Ssg);
    }
}

// ---------- launcher ----------
extern "C" void kernel_launch(void* const* d_in, const int* in_sizes, int n_in,
                              void* d_out, int out_size, void* d_ws, size_t ws_size,
                              hipStream_t stream) {
    const float* xc = (const float*)d_in[0];
    const float* yc = (const float*)d_in[1];
    const float* xt = (const float*)d_in[2];
    const float* ls_psi = (const float*)d_in[3];
    const float* os_psi = (const float*)d_in[4];
    const float* ls_rho = (const float*)d_in[5];
    const float* os_rho = (const float*)d_in[6];
    const float* w1 = (const float*)d_in[7];
    const float* b1 = (const float*)d_in[8];
    const float* w2 = (const float*)d_in[9];
    const float* b2 = (const float*)d_in[10];
    const float* w3 = (const float*)d_in[11];
    const float* b3 = (const float*)d_in[12];
    const float* w4 = (const float*)d_in[13];
    const float* b4 = (const float*)d_in[14];

    char* ws = (char*)d_ws;
    float* mm = (float*)ws;                    // 8 B
    float* f  = (float*)(ws + 64);             // 256 KB

    int ntiles = (T_GRID + TILE - 1) / TILE;   // 19
    k_fused<<<dim3(ntiles, BATCH), dim3(256), 0, stream>>>(
        (const float4*)xc, (const float4*)xt, xc, yc, ls_psi, os_psi,
        w1, b1, w2, b2, w3, b3, w4, b4, mm, f);

    k_out<<<dim3(NT / 64, BATCH), dim3(256), 0, stream>>>(
        xt, ls_rho, os_rho, mm, (const float2*)f, (float2*)d_out);
}

// Round 5
// 113.010 us; speedup vs baseline: 1.1523x; 1.1523x over previous
//
#include <hip/hip_runtime.h>
#include <math.h>

#define T_GRID 2048
#define NC 2048
#define NT 2048
#define BATCH 16
#define XCUT 28.0f        // exp2(-0.72135*28) ~ 2^-20 per-point truncation
#define TILE 112
#define BW 133            // 132 used cols + 1: row stride 133 (5 mod 32) -> conflict-free strip writes
#define PCAP 768          // filtered-point LDS capacity (expected ~245)
#define NSB 32            // sub-bins for per-t windowing

// =====================================================================
// K1: single-block min/max, 1024 threads, 16 independent float4 loads/thread
// =====================================================================
__global__ __launch_bounds__(1024) void k_minmax(const float4* __restrict__ xc4,
                                                 const float4* __restrict__ xt4,
                                                 float* __restrict__ mm) {
    float4 va[8], vb[8];
    int tid = threadIdx.x;
#pragma unroll
    for (int k = 0; k < 8; k++) va[k] = xc4[tid + 1024 * k];   // 8192 float4 total
#pragma unroll
    for (int k = 0; k < 8; k++) vb[k] = xt4[tid + 1024 * k];
    float lo = 3.4e38f, hi = -3.4e38f;
#pragma unroll
    for (int k = 0; k < 8; k++) {
        lo = fminf(lo, fminf(fminf(va[k].x, va[k].y), fminf(va[k].z, va[k].w)));
        hi = fmaxf(hi, fmaxf(fmaxf(va[k].x, va[k].y), fmaxf(va[k].z, va[k].w)));
        lo = fminf(lo, fminf(fminf(vb[k].x, vb[k].y), fminf(vb[k].z, vb[k].w)));
        hi = fmaxf(hi, fmaxf(fmaxf(vb[k].x, vb[k].y), fmaxf(vb[k].z, vb[k].w)));
    }
    for (int off = 32; off; off >>= 1) {
        lo = fminf(lo, __shfl_down(lo, off));
        hi = fmaxf(hi, __shfl_down(hi, off));
    }
    __shared__ float slo[16], shi[16];
    int lane = tid & 63, wv = tid >> 6;
    if (lane == 0) { slo[wv] = lo; shi[wv] = hi; }
    __syncthreads();
    if (tid == 0) {
        for (int w = 1; w < 16; w++) { lo = fminf(lo, slo[w]); hi = fmaxf(hi, shi[w]); }
        mm[0] = lo; mm[1] = hi;
    }
}

// =====================================================================
// K2: fused filter+bucket -> h (RBF smoother) -> conv x4.  512 threads.
// grid (19, 16). Writes f (float2 per grid point).
// =====================================================================
__global__ __launch_bounds__(512) void k_fused(
        const float* __restrict__ xc, const float* __restrict__ yc,
        const float* __restrict__ ls_psi, const float* __restrict__ os_psi,
        const float* __restrict__ mm,
        const float* __restrict__ w1, const float* __restrict__ b1,
        const float* __restrict__ w2, const float* __restrict__ b2,
        const float* __restrict__ w3, const float* __restrict__ b3,
        const float* __restrict__ w4, const float* __restrict__ b4,
        float* __restrict__ f) {
    __shared__ float rep[3][BW];
    __shared__ float L1s[16][BW];                      // layer-1 out; aliased as layer-3 out
    __shared__ __align__(16) char pool[32 * BW * 4];   // 17024 B: layer-2 out; early: px/py/part/bins
    __shared__ float w1L[15][16];
    __shared__ float w2L[80][32];
    __shared__ float w3L[160][16];
    __shared__ float w4L[80][2];
    __shared__ float bL[66];

    float (*L2s)[BW] = reinterpret_cast<float (*)[BW]>(pool);
    float (*L3s)[BW] = L1s;
    float*  px     = reinterpret_cast<float*>(pool);              // [0, 3072)
    float*  py     = reinterpret_cast<float*>(pool + 3072);       // [3072, 6144)
    float2* part   = reinterpret_cast<float2*>(pool + 6144);      // 512 float2 [6144, 10240)
    int*    bstart = reinterpret_cast<int*>(pool + 10240);        // 33 ints
    int*    curi   = reinterpret_cast<int*>(pool + 10376);        // 32 ints

    int tid = threadIdx.x;
    int b = blockIdx.y;
    int gstart = blockIdx.x * TILE - 8;

    // ---- stage weights/biases ----
    for (int idx = tid; idx < 240; idx += 512)  { int o = idx / 15,  r2 = idx % 15;  w1L[r2][o] = w1[idx]; }
    for (int idx = tid; idx < 2560; idx += 512) { int o = idx / 80,  r2 = idx % 80;  w2L[r2][o] = w2[idx]; }
    for (int idx = tid; idx < 2560; idx += 512) { int o = idx / 160, r2 = idx % 160; w3L[r2][o] = w3[idx]; }
    for (int idx = tid; idx < 160; idx += 512)  { int o = idx / 80,  r2 = idx % 80;  w4L[r2][o] = w4[idx]; }
    if (tid < 16) bL[tid] = b1[tid];
    if (tid < 32) bL[16 + tid] = b2[tid];
    if (tid < 16) bL[48 + tid] = b3[tid];
    if (tid < 2)  bL[64 + tid] = b4[tid];
    if (tid < 4) {                                     // zero rep/L1 pad cols 0,1,130,131
        int c = (tid < 2) ? tid : tid + 128;
        for (int r2 = 0; r2 < 3; r2++)  rep[r2][c] = 0.f;
        for (int r2 = 0; r2 < 16; r2++) L1s[r2][c] = 0.f;
    }

    float lower = mm[0], upper = mm[1];
    float step = (upper - lower) * (1.0f / (T_GRID - 1));
    float ls = ls_psi[0], os = os_psi[0];
    float c2 = -0.72134752044f / (ls * ls);            // -0.5*log2(e)/ls^2
    float R = ls * sqrtf(XCUT);

    int g0 = max(gstart, 0), g1 = min(gstart + 127, T_GRID - 1);
    float tmin = fmaf((float)g0, step, lower) - R;
    float tmax = fmaf((float)g1, step, lower) + R;
    float sbw_inv = (float)NSB / (tmax - tmin);

    // ---- filter own batch's points into tile box, bucket into NSB sub-bins ----
    if (tid < NSB + 1) bstart[tid] = 0;
    __syncthreads();
    float xv[4], yv[4];
    int bn[4];
    const float* xb = xc + b * NC;
    const float* yb = yc + b * NC;
#pragma unroll
    for (int k = 0; k < 4; k++) {
        int idx = tid + 512 * k;
        xv[k] = xb[idx];
        yv[k] = yb[idx];
        bool in = (xv[k] >= tmin) & (xv[k] <= tmax);
        bn[k] = -1;
        if (in) {
            bn[k] = min(NSB - 1, max(0, (int)((xv[k] - tmin) * sbw_inv)));
            atomicAdd(&bstart[bn[k]], 1);
        }
    }
    __syncthreads();
    if (tid == 0) {
        int run = 0;
        for (int i = 0; i < NSB; i++) { int c = bstart[i]; bstart[i] = run; run += c; }
        bstart[NSB] = run;
    }
    __syncthreads();
    if (tid < NSB) curi[tid] = bstart[tid];
    __syncthreads();
#pragma unroll
    for (int k = 0; k < 4; k++) {
        if (bn[k] >= 0) {
            int pos = atomicAdd(&curi[bn[k]], 1);
            if (pos < PCAP) { px[pos] = xv[k]; py[pos] = yv[k]; }
        }
    }
    __syncthreads();

    // ---- h-phase: 4 threads per position ----
    {
        int p = tid & 127, rr = tid >> 7;              // rr in {0..3}
        int gp = gstart + p;
        bool pvalid = (gp >= 0 && gp < T_GRID);
        float t = fmaf((float)gp, step, lower);
        int s = 0, e = 0;
        if (pvalid) {
            int b0 = min(NSB - 1, max(0, (int)((t - R - tmin) * sbw_inv)));
            int b1 = min(NSB - 1, max(0, (int)((t + R - tmin) * sbw_inv)));
            s = bstart[b0];
            e = min(bstart[b1 + 1], PCAP);
        }
        float S0 = 0.f, S1 = 0.f;
        for (int j = s + rr; j < e; j += 4) {
            float xj = px[j], yj = py[j];
            float d = t - xj;
            float ev = exp2f(d * d * c2);
            S0 += ev;
            S1 = fmaf(ev, yj, S1);
        }
        part[tid] = make_float2(S0, S1);               // disjoint from px/py: no sync needed
        __syncthreads();
        if (tid < 128) {
            float2 q1 = part[tid + 128], q2 = part[tid + 256], q3 = part[tid + 384];
            S0 += q1.x + q2.x + q3.x;
            S1 += q1.y + q2.y + q3.y;
            float h0 = os * S0;
            float h1 = os * S1 / (h0 + 1e-8f);
            rep[0][p + 2] = pvalid ? t : 0.f;
            rep[1][p + 2] = pvalid ? h0 : 0.f;
            rep[2][p + 2] = pvalid ? h1 : 0.f;
        }
    }
    __syncthreads();                                   // pool (px/py/part/bins) dead now

    // ---- layer 1: 3 -> 16, relu. o=tid&15, 32 groups x 4 positions ----
    {
        if (tid < 4) {                                 // zero L2 pad cols
            int c = (tid < 2) ? tid : tid + 128;
            for (int r2 = 0; r2 < 32; r2++) L2s[r2][c] = 0.f;
        }
        int o = tid & 15, s0 = (tid >> 4) << 2;
        float acc[4];
        float bias = bL[o];
#pragma unroll
        for (int s = 0; s < 4; s++) acc[s] = bias;
        for (int i = 0; i < 3; i++) {
            float x[8];
#pragma unroll
            for (int j = 0; j < 8; j++) x[j] = rep[i][s0 + j];
#pragma unroll
            for (int k = 0; k < 5; k++) {
                float w = w1L[i * 5 + k][o];
#pragma unroll
                for (int s = 0; s < 4; s++) acc[s] = fmaf(x[s + k], w, acc[s]);
            }
        }
#pragma unroll
        for (int s = 0; s < 4; s++) {
            int p = s0 + s, gp = gstart + p;
            bool vv = (p >= 2 && p < 126 && gp >= 0 && gp < T_GRID);
            L1s[o][p + 2] = vv ? fmaxf(acc[s], 0.f) : 0.f;
        }
    }
    __syncthreads();

    // ---- layer 2: 16 -> 32, relu. o=tid&31, 16 groups x 8 positions ----
    {
        int o = tid & 31, s0 = (tid >> 5) << 3;
        float acc[8];
        float bias = bL[16 + o];
#pragma unroll
        for (int s = 0; s < 8; s++) acc[s] = bias;
        for (int i = 0; i < 16; i++) {
            float x[12];
#pragma unroll
            for (int j = 0; j < 12; j++) x[j] = L1s[i][s0 + j];
#pragma unroll
            for (int k = 0; k < 5; k++) {
                float w = w2L[i * 5 + k][o];
#pragma unroll
                for (int s = 0; s < 8; s++) acc[s] = fmaf(x[s + k], w, acc[s]);
            }
        }
#pragma unroll
        for (int s = 0; s < 8; s++) {
            int p = s0 + s, gp = gstart + p;
            bool vv = (p >= 4 && p < 124 && gp >= 0 && gp < T_GRID);
            L2s[o][p + 2] = vv ? fmaxf(acc[s], 0.f) : 0.f;
        }
    }
    __syncthreads();

    // ---- layer 3: 32 -> 16, relu. writes into L1 storage (dead). ----
    {
        int o = tid & 15, s0 = (tid >> 4) << 2;
        float acc[4];
        float bias = bL[48 + o];
#pragma unroll
        for (int s = 0; s < 4; s++) acc[s] = bias;
        for (int i = 0; i < 32; i++) {
            float x[8];
#pragma unroll
            for (int j = 0; j < 8; j++) x[j] = L2s[i][s0 + j];
#pragma unroll
            for (int k = 0; k < 5; k++) {
                float w = w3L[i * 5 + k][o];
#pragma unroll
                for (int s = 0; s < 4; s++) acc[s] = fmaf(x[s + k], w, acc[s]);
            }
        }
        __syncthreads();                               // all L1 reads done before alias overwrite
#pragma unroll
        for (int s = 0; s < 4; s++) {
            int p = s0 + s, gp = gstart + p;
            bool vv = (p >= 6 && p < 122 && gp >= 0 && gp < T_GRID);
            L3s[o][p + 2] = vv ? fmaxf(acc[s], 0.f) : 0.f;
        }
    }
    __syncthreads();

    // ---- layer 4: 16 -> 2 + softplus; threads 0..255 ----
    if (tid < 256) {
        int o = tid & 1, p = tid >> 1;
        float a = bL[64 + o];
        for (int i = 0; i < 16; i++) {
#pragma unroll
            for (int k = 0; k < 5; k++) {
                a = fmaf(L3s[i][p + k], w4L[i * 5 + k][o], a);
            }
        }
        int gp = gstart + p;
        if (p >= 8 && p < 120 && gp >= 0 && gp < T_GRID) {
            if (o) {
                float sp = fmaxf(a, 0.f) + log1pf(expf(-fabsf(a)));
                f[2 * (b * T_GRID + gp) + 1] = sp;
            } else {
                f[2 * (b * T_GRID + gp)] = a;
            }
        }
    }
}

// =====================================================================
// K3: windowed out = RBF(xt, t) @ [f_mu, f_sp], 4 threads per xt
// =====================================================================
__global__ __launch_bounds__(256) void k_out(const float* __restrict__ xt,
                                             const float* __restrict__ ls_rho,
                                             const float* __restrict__ os_rho,
                                             const float* __restrict__ mm,
                                             const float2* __restrict__ f,
                                             float2* __restrict__ out) {
    __shared__ float smx[T_GRID];
    __shared__ float ssg[T_GRID];
    __shared__ float2 part[256];
    int b = blockIdx.y, tid = threadIdx.x;
    int it = blockIdx.x * 64 + (tid & 63);
    int r = tid >> 6;
    float lower = mm[0], upper = mm[1];
    float step = (upper - lower) * (1.0f / (T_GRID - 1));
    float invstep = 1.0f / step;
    float ls = ls_rho[0], os = os_rho[0];
    float c2 = -0.72134752044f / (ls * ls);
    float R = ls * sqrtf(XCUT);
    float x = xt[b * NT + it];

    const float2* fb = f + b * T_GRID;
    for (int k = tid; k < T_GRID; k += 256) {
        float2 v = fb[k];
        smx[k] = v.x; ssg[k] = v.y;
    }
    __syncthreads();

    int j0 = max(0, (int)floorf((x - R - lower) * invstep));
    int j1 = min(T_GRID - 1, (int)ceilf((x + R - lower) * invstep));

    float Smu = 0.f, Ssg = 0.f;
    float jf = (float)(j0 + r);
    for (int j = j0 + r; j <= j1; j += 4) {
        float d = x - fmaf(jf, step, lower);
        float e = exp2f(d * d * c2);
        Smu = fmaf(e, smx[j], Smu);
        Ssg = fmaf(e, ssg[j], Ssg);
        jf += 4.0f;
    }
    part[tid] = make_float2(Smu, Ssg);
    __syncthreads();
    if (r == 0) {
#pragma unroll
        for (int q = 64; q < 256; q += 64) {
            float2 pp = part[tid + q];
            Smu += pp.x; Ssg += pp.y;
        }
        out[b * NT + it] = make_float2(os * Smu, os * Ssg);
    }
}

// ---------- launcher ----------
extern "C" void kernel_launch(void* const* d_in, const int* in_sizes, int n_in,
                              void* d_out, int out_size, void* d_ws, size_t ws_size,
                              hipStream_t stream) {
    const float* xc = (const float*)d_in[0];
    const float* yc = (const float*)d_in[1];
    const float* xt = (const float*)d_in[2];
    const float* ls_psi = (const float*)d_in[3];
    const float* os_psi = (const float*)d_in[4];
    const float* ls_rho = (const float*)d_in[5];
    const float* os_rho = (const float*)d_in[6];
    const float* w1 = (const float*)d_in[7];
    const float* b1 = (const float*)d_in[8];
    const float* w2 = (const float*)d_in[9];
    const float* b2 = (const float*)d_in[10];
    const float* w3 = (const float*)d_in[11];
    const float* b3 = (const float*)d_in[12];
    const float* w4 = (const float*)d_in[13];
    const float* b4 = (const float*)d_in[14];

    char* ws = (char*)d_ws;
    float* mm = (float*)ws;                    // 8 B
    float* f  = (float*)(ws + 64);             // 256 KB

    k_minmax<<<dim3(1), dim3(1024), 0, stream>>>((const float4*)xc, (const float4*)xt, mm);

    int ntiles = (T_GRID + TILE - 1) / TILE;   // 19
    k_fused<<<dim3(ntiles, BATCH), dim3(512), 0, stream>>>(
        xc, yc, ls_psi, os_psi, mm,
        w1, b1, w2, b2, w3, b3, w4, b4, f);

    k_out<<<dim3(NT / 64, BATCH), dim3(256), 0, stream>>>(
        xt, ls_rho, os_rho, mm, (const float2*)f, (float2*)d_out);
}

// Round 6
// 109.589 us; speedup vs baseline: 1.1883x; 1.0312x over previous
//
#include <hip/hip_runtime.h>
#include <math.h>

#define T_GRID 2048
#define NC 2048
#define NT 2048
#define BATCH 16
#define XCUT 28.0f        // exp2(-0.72135*28) ~ 2^-20 per-point truncation
#define TILE 128          // output positions per block -> 16 x-tiles exactly
#define SW 144            // staged positions (TILE + 8 halo each side)
#define W 149             // row width: 2 pad + 144 + 2 pad + 1 (149 coprime 32)
#define PCAP 768          // filtered-point LDS capacity (expected ~260)
#define NSB 32            // sub-bins for per-t windowing

// =====================================================================
// K1: single-block min/max, 1024 threads, 16 independent float4 loads/thread
// =====================================================================
__global__ __launch_bounds__(1024) void k_minmax(const float4* __restrict__ xc4,
                                                 const float4* __restrict__ xt4,
                                                 float* __restrict__ mm) {
    float4 va[8], vb[8];
    int tid = threadIdx.x;
#pragma unroll
    for (int k = 0; k < 8; k++) va[k] = xc4[tid + 1024 * k];
#pragma unroll
    for (int k = 0; k < 8; k++) vb[k] = xt4[tid + 1024 * k];
    float lo = 3.4e38f, hi = -3.4e38f;
#pragma unroll
    for (int k = 0; k < 8; k++) {
        lo = fminf(lo, fminf(fminf(va[k].x, va[k].y), fminf(va[k].z, va[k].w)));
        hi = fmaxf(hi, fmaxf(fmaxf(va[k].x, va[k].y), fmaxf(va[k].z, va[k].w)));
        lo = fminf(lo, fminf(fminf(vb[k].x, vb[k].y), fminf(vb[k].z, vb[k].w)));
        hi = fmaxf(hi, fmaxf(fmaxf(vb[k].x, vb[k].y), fmaxf(vb[k].z, vb[k].w)));
    }
    for (int off = 32; off; off >>= 1) {
        lo = fminf(lo, __shfl_down(lo, off));
        hi = fmaxf(hi, __shfl_down(hi, off));
    }
    __shared__ float slo[16], shi[16];
    int lane = tid & 63, wv = tid >> 6;
    if (lane == 0) { slo[wv] = lo; shi[wv] = hi; }
    __syncthreads();
    if (tid == 0) {
        for (int w = 1; w < 16; w++) { lo = fminf(lo, slo[w]); hi = fmaxf(hi, shi[w]); }
        mm[0] = lo; mm[1] = hi;
    }
}

// =====================================================================
// K2: fused filter+bucket -> h (RBF smoother) -> conv x4.  576 threads.
// grid (16, 16) = 256 blocks = 1/CU. Writes f (float2 per grid point).
// =====================================================================
__global__ __launch_bounds__(576) void k_fused(
        const float* __restrict__ xc, const float* __restrict__ yc,
        const float* __restrict__ ls_psi, const float* __restrict__ os_psi,
        const float* __restrict__ mm,
        const float* __restrict__ w1, const float* __restrict__ b1,
        const float* __restrict__ w2, const float* __restrict__ b2,
        const float* __restrict__ w3, const float* __restrict__ b3,
        const float* __restrict__ w4, const float* __restrict__ b4,
        float* __restrict__ f) {
    __shared__ float rep[3][W];
    __shared__ float L1s[16][W];                       // layer-1 out; aliased as layer-3 out
    __shared__ __align__(16) char pool[32 * W * 4];    // 19072 B: layer-2 out; early: px/py/part/bins
    __shared__ float w1L[15][16];
    __shared__ float w2L[80][32];
    __shared__ float w3L[160][16];
    __shared__ float w4L[80][2];
    __shared__ float bL[66];

    float (*L2s)[W] = reinterpret_cast<float (*)[W]>(pool);
    float (*L3s)[W] = L1s;
    float*  px     = reinterpret_cast<float*>(pool);              // [0, 3072)
    float*  py     = reinterpret_cast<float*>(pool + 3072);       // [3072, 6144)
    float2* part   = reinterpret_cast<float2*>(pool + 6144);      // 576 float2 [6144, 10752)
    int*    bstart = reinterpret_cast<int*>(pool + 10752);        // 33 ints
    int*    curi   = reinterpret_cast<int*>(pool + 10896);        // 32 ints

    int tid = threadIdx.x;
    int b = blockIdx.y;
    int gstart = blockIdx.x * TILE - 8;                // staged gp = gstart + p, p in [0,SW)

    // ---- stage weights/biases ----
    for (int idx = tid; idx < 240; idx += 576)  { int o = idx / 15,  r2 = idx % 15;  w1L[r2][o] = w1[idx]; }
    for (int idx = tid; idx < 2560; idx += 576) { int o = idx / 80,  r2 = idx % 80;  w2L[r2][o] = w2[idx]; }
    for (int idx = tid; idx < 2560; idx += 576) { int o = idx / 160, r2 = idx % 160; w3L[r2][o] = w3[idx]; }
    for (int idx = tid; idx < 160; idx += 576)  { int o = idx / 80,  r2 = idx % 80;  w4L[r2][o] = w4[idx]; }
    if (tid < 16) bL[tid] = b1[tid];
    if (tid < 32) bL[16 + tid] = b2[tid];
    if (tid < 16) bL[48 + tid] = b3[tid];
    if (tid < 2)  bL[64 + tid] = b4[tid];
    if (tid < 4) {                                     // zero rep/L1 pad cols 0,1,146,147
        int c = (tid < 2) ? tid : tid + SW;
        for (int r2 = 0; r2 < 3; r2++)  rep[r2][c] = 0.f;
        for (int r2 = 0; r2 < 16; r2++) L1s[r2][c] = 0.f;
    }

    float lower = mm[0], upper = mm[1];
    float step = (upper - lower) * (1.0f / (T_GRID - 1));
    float ls = ls_psi[0], os = os_psi[0];
    float c2 = -0.72134752044f / (ls * ls);            // -0.5*log2(e)/ls^2
    float R = ls * sqrtf(XCUT);

    int g0 = max(gstart, 0), g1 = min(gstart + SW - 1, T_GRID - 1);
    float tmin = fmaf((float)g0, step, lower) - R;
    float tmax = fmaf((float)g1, step, lower) + R;
    float sbw_inv = (float)NSB / (tmax - tmin);

    // ---- filter own batch's points into tile box, bucket into NSB sub-bins ----
    if (tid < NSB + 1) bstart[tid] = 0;
    __syncthreads();
    float xv[4], yv[4];
    int bn[4];
    const float* xb = xc + b * NC;
    const float* yb = yc + b * NC;
#pragma unroll
    for (int k = 0; k < 4; k++) {
        int idx = tid + 576 * k;
        bn[k] = -1;
        if (idx < NC) {
            xv[k] = xb[idx];
            yv[k] = yb[idx];
            if ((xv[k] >= tmin) & (xv[k] <= tmax)) {
                bn[k] = min(NSB - 1, max(0, (int)((xv[k] - tmin) * sbw_inv)));
                atomicAdd(&bstart[bn[k]], 1);
            }
        }
    }
    __syncthreads();
    if (tid == 0) {
        int run = 0;
        for (int i = 0; i < NSB; i++) { int c = bstart[i]; bstart[i] = run; run += c; }
        bstart[NSB] = run;
    }
    __syncthreads();
    if (tid < NSB) curi[tid] = bstart[tid];
    __syncthreads();
#pragma unroll
    for (int k = 0; k < 4; k++) {
        if (bn[k] >= 0) {
            int pos = atomicAdd(&curi[bn[k]], 1);
            if (pos < PCAP) { px[pos] = xv[k]; py[pos] = yv[k]; }
        }
    }
    __syncthreads();

    // ---- h-phase: 4 threads per staged position (576 = 4 x 144) ----
    {
        int p = tid >> 2, rr = tid & 3;                // p in [0,144)
        int gp = gstart + p;
        bool pvalid = (gp >= 0 && gp < T_GRID);
        float t = fmaf((float)gp, step, lower);
        int s = 0, e = 0;
        if (pvalid) {
            int b0 = min(NSB - 1, max(0, (int)((t - R - tmin) * sbw_inv)));
            int b1 = min(NSB - 1, max(0, (int)((t + R - tmin) * sbw_inv)));
            s = bstart[b0];
            e = min(bstart[b1 + 1], PCAP);
        }
        float S0 = 0.f, S1 = 0.f;
        for (int j = s + rr; j < e; j += 4) {
            float xj = px[j], yj = py[j];
            float d = t - xj;
            float ev = exp2f(d * d * c2);
            S0 += ev;
            S1 = fmaf(ev, yj, S1);
        }
        part[rr * SW + p] = make_float2(S0, S1);       // disjoint from px/py; stride-SW: 2-way banks
        __syncthreads();
        if (tid < SW) {
            float2 q0 = part[tid], q1 = part[tid + SW], q2 = part[tid + 2 * SW], q3 = part[tid + 3 * SW];
            float T0 = q0.x + q1.x + q2.x + q3.x;
            float T1 = q0.y + q1.y + q2.y + q3.y;
            int gp2 = gstart + tid;
            bool pv2 = (gp2 >= 0 && gp2 < T_GRID);
            float h0 = os * T0;
            float h1 = os * T1 / (h0 + 1e-8f);
            rep[0][tid + 2] = pv2 ? fmaf((float)gp2, step, lower) : 0.f;
            rep[1][tid + 2] = pv2 ? h0 : 0.f;
            rep[2][tid + 2] = pv2 ? h1 : 0.f;
        }
    }
    __syncthreads();                                   // pool (px/py/part/bins) dead now

    // ---- layer 1: 3 -> 16, relu. o=tid&15, 36 groups x strip 4 ----
    {
        if (tid < 4) {                                 // zero L2 pad cols
            int c = (tid < 2) ? tid : tid + SW;
            for (int r2 = 0; r2 < 32; r2++) L2s[r2][c] = 0.f;
        }
        int o = tid & 15, s0 = (tid >> 4) << 2;        // s0 in {0,4,...,140}
        float acc[4];
        float bias = bL[o];
#pragma unroll
        for (int s = 0; s < 4; s++) acc[s] = bias;
        for (int i = 0; i < 3; i++) {
            float x[8];
#pragma unroll
            for (int j = 0; j < 8; j++) x[j] = rep[i][s0 + j];
#pragma unroll
            for (int k = 0; k < 5; k++) {
                float w = w1L[i * 5 + k][o];
#pragma unroll
                for (int s = 0; s < 4; s++) acc[s] = fmaf(x[s + k], w, acc[s]);
            }
        }
#pragma unroll
        for (int s = 0; s < 4; s++) {
            int p = s0 + s, gp = gstart + p;
            bool vv = (p >= 2 && p < SW - 2 && gp >= 0 && gp < T_GRID);
            L1s[o][p + 2] = vv ? fmaxf(acc[s], 0.f) : 0.f;
        }
    }
    __syncthreads();

    // ---- layer 2: 16 -> 32, relu. o=tid&31, 18 groups x strip 8 ----
    {
        int o = tid & 31, s0 = (tid >> 5) << 3;        // s0 in {0,8,...,136}
        float acc[8];
        float bias = bL[16 + o];
#pragma unroll
        for (int s = 0; s < 8; s++) acc[s] = bias;
        for (int i = 0; i < 16; i++) {
            float x[12];
#pragma unroll
            for (int j = 0; j < 12; j++) x[j] = L1s[i][s0 + j];
#pragma unroll
            for (int k = 0; k < 5; k++) {
                float w = w2L[i * 5 + k][o];
#pragma unroll
                for (int s = 0; s < 8; s++) acc[s] = fmaf(x[s + k], w, acc[s]);
            }
        }
#pragma unroll
        for (int s = 0; s < 8; s++) {
            int p = s0 + s, gp = gstart + p;
            bool vv = (p >= 4 && p < SW - 4 && gp >= 0 && gp < T_GRID);
            L2s[o][p + 2] = vv ? fmaxf(acc[s], 0.f) : 0.f;
        }
    }
    __syncthreads();

    // ---- layer 3: 32 -> 16, relu. writes into L1 storage (dead alias, disjoint from L2s) ----
    {
        int o = tid & 15, s0 = (tid >> 4) << 2;
        float acc[4];
        float bias = bL[48 + o];
#pragma unroll
        for (int s = 0; s < 4; s++) acc[s] = bias;
        for (int i = 0; i < 32; i++) {
            float x[8];
#pragma unroll
            for (int j = 0; j < 8; j++) x[j] = L2s[i][s0 + j];
#pragma unroll
            for (int k = 0; k < 5; k++) {
                float w = w3L[i * 5 + k][o];
#pragma unroll
                for (int s = 0; s < 4; s++) acc[s] = fmaf(x[s + k], w, acc[s]);
            }
        }
#pragma unroll
        for (int s = 0; s < 4; s++) {
            int p = s0 + s, gp = gstart + p;
            bool vv = (p >= 6 && p < SW - 6 && gp >= 0 && gp < T_GRID);
            L3s[o][p + 2] = vv ? fmaxf(acc[s], 0.f) : 0.f;
        }
    }
    __syncthreads();

    // ---- layer 4: 16 -> 2 + softplus; threads 0..255, outputs land exactly on [0,T) ----
    if (tid < 256) {
        int o = tid & 1, po = tid >> 1;                // po in [0,128)
        float a = bL[64 + o];
        for (int i = 0; i < 16; i++) {
#pragma unroll
            for (int k = 0; k < 5; k++) {
                a = fmaf(L3s[i][po + 8 + k], w4L[i * 5 + k][o], a);
            }
        }
        int gp = blockIdx.x * TILE + po;               // in [0,2048) always
        if (o) {
            float sp = fmaxf(a, 0.f) + log1pf(expf(-fabsf(a)));
            f[2 * (b * T_GRID + gp) + 1] = sp;
        } else {
            f[2 * (b * T_GRID + gp)] = a;
        }
    }
}

// =====================================================================
// K3: windowed out = RBF(xt, t) @ [f_mu, f_sp], 4 threads per xt
// =====================================================================
__global__ __launch_bounds__(256) void k_out(const float* __restrict__ xt,
                                             const float* __restrict__ ls_rho,
                                             const float* __restrict__ os_rho,
                                             const float* __restrict__ mm,
                                             const float2* __restrict__ f,
                                             float2* __restrict__ out) {
    __shared__ float smx[T_GRID];
    __shared__ float ssg[T_GRID];
    __shared__ float2 part[256];
    int b = blockIdx.y, tid = threadIdx.x;
    int it = blockIdx.x * 64 + (tid & 63);
    int r = tid >> 6;
    float lower = mm[0], upper = mm[1];
    float step = (upper - lower) * (1.0f / (T_GRID - 1));
    float invstep = 1.0f / step;
    float ls = ls_rho[0], os = os_rho[0];
    float c2 = -0.72134752044f / (ls * ls);
    float R = ls * sqrtf(XCUT);
    float x = xt[b * NT + it];

    const float2* fb = f + b * T_GRID;
    for (int k = tid; k < T_GRID; k += 256) {
        float2 v = fb[k];
        smx[k] = v.x; ssg[k] = v.y;
    }
    __syncthreads();

    int j0 = max(0, (int)floorf((x - R - lower) * invstep));
    int j1 = min(T_GRID - 1, (int)ceilf((x + R - lower) * invstep));

    float Smu = 0.f, Ssg = 0.f;
    float jf = (float)(j0 + r);
    for (int j = j0 + r; j <= j1; j += 4) {
        float d = x - fmaf(jf, step, lower);
        float e = exp2f(d * d * c2);
        Smu = fmaf(e, smx[j], Smu);
        Ssg = fmaf(e, ssg[j], Ssg);
        jf += 4.0f;
    }
    part[tid] = make_float2(Smu, Ssg);
    __syncthreads();
    if (r == 0) {
#pragma unroll
        for (int q = 64; q < 256; q += 64) {
            float2 pp = part[tid + q];
            Smu += pp.x; Ssg += pp.y;
        }
        out[b * NT + it] = make_float2(os * Smu, os * Ssg);
    }
}

// ---------- launcher ----------
extern "C" void kernel_launch(void* const* d_in, const int* in_sizes, int n_in,
                              void* d_out, int out_size, void* d_ws, size_t ws_size,
                              hipStream_t stream) {
    const float* xc = (const float*)d_in[0];
    const float* yc = (const float*)d_in[1];
    const float* xt = (const float*)d_in[2];
    const float* ls_psi = (const float*)d_in[3];
    const float* os_psi = (const float*)d_in[4];
    const float* ls_rho = (const float*)d_in[5];
    const float* os_rho = (const float*)d_in[6];
    const float* w1 = (const float*)d_in[7];
    const float* b1 = (const float*)d_in[8];
    const float* w2 = (const float*)d_in[9];
    const float* b2 = (const float*)d_in[10];
    const float* w3 = (const float*)d_in[11];
    const float* b3 = (const float*)d_in[12];
    const float* w4 = (const float*)d_in[13];
    const float* b4 = (const float*)d_in[14];

    char* ws = (char*)d_ws;
    float* mm = (float*)ws;                    // 8 B
    float* f  = (float*)(ws + 64);             // 256 KB

    k_minmax<<<dim3(1), dim3(1024), 0, stream>>>((const float4*)xc, (const float4*)xt, mm);

    k_fused<<<dim3(T_GRID / TILE, BATCH), dim3(576), 0, stream>>>(
        xc, yc, ls_psi, os_psi, mm,
        w1, b1, w2, b2, w3, b3, w4, b4, f);

    k_out<<<dim3(NT / 64, BATCH), dim3(256), 0, stream>>>(
        xt, ls_rho, os_rho, mm, (const float2*)f, (float2*)d_out);
}